// Round 2
// baseline (333.035 us; speedup 1.0000x reference)
//
#include <hip/hip_runtime.h>
#include <hip/hip_bf16.h>

// RestrictedNN DAG. Round 7: revert to 2048-block tree (round-5 structure,
// 3 blocks/CU) + fuse root via per-tile completion counter:
//  - each batch tile (16 rows) is covered by 8 slice-blocks; after phase C
//    each block does release-fence + atomicAdd(cnt[tile]); the last of the 8
//    acquires and runs the 128->16->1 root for its 16 rows in-block.
//  - k_root kernel and its launch gap are gone; h2 read is L2/L3-hot.
// B=4096, L0=512 leaves (G=8,H=16), L1=64, L2=8 (FAN=8), root 128->16.

#define TB 16
#define XSS 520      // ushorts per x row (512+8): rows 16B-aligned; 260dw==4 mod 32
#define H0S 1032     // ushorts per h0 row (1024+8): rows 16B-aligned; 516dw==4 mod 32
#define H1S 136      // ushorts per h1 row (128+8): rows 16B-aligned

typedef __attribute__((ext_vector_type(8))) short short8;
typedef __attribute__((ext_vector_type(4))) float floatx4;

__device__ __forceinline__ float sigf(float v) {
    return __builtin_amdgcn_rcpf(1.0f + __expf(-v));
}
__device__ __forceinline__ float bflo(unsigned int p) {
    return __builtin_bit_cast(float, p << 16);
}
__device__ __forceinline__ float bfhi(unsigned int p) {
    return __builtin_bit_cast(float, p & 0xffff0000u);
}
__device__ __forceinline__ unsigned int f2bf_u32(float f) {   // RNE, bf16 in low 16
    unsigned int u = __builtin_bit_cast(unsigned int, f);
    return (u + 0x7fffu + ((u >> 16) & 1u)) >> 16;
}
__device__ __forceinline__ unsigned short f2bf(float f) {
    return (unsigned short)f2bf_u32(f);
}
__device__ __forceinline__ unsigned int f2bf2(float lo, float hi) {
    return f2bf_u32(lo) | (f2bf_u32(hi) << 16);
}

// ---- prep: transpose W1/W2 per module to bf16 [h][k] fragment layout ----
//      + zero the per-tile completion counters (block 0)
__global__ __launch_bounds__(256) void k_prep(
    const float* __restrict__ W1, const float* __restrict__ W2,
    unsigned short* __restrict__ W1t, unsigned short* __restrict__ W2t,
    int* __restrict__ cnt)
{
    __shared__ float wl[128 * 17];
    const int mb = blockIdx.x;              // 0..63 -> W1, 64..71 -> W2
    const int tid = threadIdx.x;
    if (mb == 0) cnt[tid] = 0;              // 256 tiles; kernel-end release
    const float* src = (mb < 64) ? (W1 + (size_t)mb * 2048)
                                 : (W2 + (size_t)(mb - 64) * 2048);
    unsigned short* dst = (mb < 64) ? (W1t + (size_t)mb * 2048)
                                    : (W2t + (size_t)(mb - 64) * 2048);
#pragma unroll
    for (int i = 0; i < 8; ++i) {
        const int idx = tid + i * 256;      // [k][h] in, coalesced
        wl[(idx >> 4) * 17 + (idx & 15)] = src[idx];
    }
    __syncthreads();
#pragma unroll
    for (int i = 0; i < 4; ++i) {
        const int u  = tid + i * 256;       // uint index over [h][k] bf16 out
        const int h  = u >> 6;
        const int k  = (u & 63) * 2;
        ((unsigned int*)dst)[u] = f2bf2(wl[k * 17 + h], wl[(k + 1) * 17 + h]);
    }
}

__global__ __launch_bounds__(256) void k_tree(
    const float* __restrict__ x, const float* __restrict__ Wg,
    const float* __restrict__ bg, const float* __restrict__ W0,
    const unsigned short* __restrict__ W1t, const unsigned short* __restrict__ W2t,
    const float* __restrict__ W3, const float* __restrict__ Wf,
    float* __restrict__ h2ws, int* __restrict__ cnt, float* __restrict__ out)
{
    __shared__ __align__(16) unsigned short xs[TB * XSS];    // 16640 B (h1/root reuse)
    __shared__ __align__(16) unsigned short h0s[TB * H0S];   // 33024 B
    __shared__ int lastflag;
    unsigned short* h1u = xs;   // h1 [b][j*16+h] bf16, stride H1S; xs dead after A

    const int tid  = threadIdx.x;
    const int s    = blockIdx.x & 7;
    const int tile = blockIdx.x >> 3;
    const int b0   = tile * TB;
    const int lane = tid & 63;
    const int wv   = tid >> 6;

    // ---------- issue x stage loads (oldest in pipe), convert as they land ----
    const float* xbase = x + (size_t)b0 * 4096 + s * 512;
    uint2 xp[8];
#pragma unroll
    for (int t = 0; t < 8; ++t) {
        const int i = tid + t * 256;           // over TB*128 float4s
        const int r = i >> 7, c4 = i & 127;
        const float4 v = *(const float4*)(xbase + (size_t)r * 4096 + c4 * 4);
        xp[t] = make_uint2(f2bf2(v.x, v.y), f2bf2(v.z, v.w));
    }

    // ---------- prefetch phase-A weights (lane-contiguous W0) ----------
    const int m_l = tid >> 2;                  // local leaf module 0..63
    const int hq  = tid & 3;                   // h quad
    const int m   = s * 64 + m_l;
    float4 w0r[8];
#pragma unroll
    for (int g = 0; g < 8; ++g)
        w0r[g] = *(const float4*)(W0 + (size_t)m * 128 + g * 16 + hq * 4);
    const float4 wg0 = *(const float4*)(Wg + m * 8);
    const float4 wg1 = *(const float4*)(Wg + m * 8 + 4);
    const float4 bg0 = *(const float4*)(bg + m * 8);
    const float4 bg1 = *(const float4*)(bg + m * 8 + 4);

    // ---------- prefetch phase-B/C MFMA B-fragments ----------
    const int n = lane & 15, q = lane >> 4;
    short8 w1r[2][4];
#pragma unroll
    for (int jj = 0; jj < 2; ++jj) {
        const unsigned short* w1m =
            W1t + ((size_t)(s * 8 + wv * 2 + jj) * 16 + n) * 128 + q * 8;
#pragma unroll
        for (int ks = 0; ks < 4; ++ks)
            w1r[jj][ks] = *(const short8*)(w1m + ks * 32);
    }
    short8 w2r[4];
    if (wv == 0) {
        const unsigned short* w2m = W2t + ((size_t)s * 16 + n) * 128 + q * 8;
#pragma unroll
        for (int ks = 0; ks < 4; ++ks) w2r[ks] = *(const short8*)(w2m + ks * 32);
    }

    // ---------- write x tile to LDS ----------
#pragma unroll
    for (int t = 0; t < 8; ++t) {
        const int i = tid + t * 256;
        const int r = i >> 7, c4 = i & 127;
        *(uint2*)&xs[r * XSS + c4 * 4] = xp[t];
    }
    __syncthreads();

    // ---------- phase A: gene + h0, loop over batch rows ----------
    {
        unsigned short* h0base = &h0s[m_l * 16 + hq * 4];
#pragma unroll 4
        for (int b = 0; b < TB; ++b) {
            const uint4 xv = *(const uint4*)&xs[b * XSS + m_l * 8];
            float gene[8];
            gene[0] = fmaf(bflo(xv.x), wg0.x, bg0.x);
            gene[1] = fmaf(bfhi(xv.x), wg0.y, bg0.y);
            gene[2] = fmaf(bflo(xv.y), wg0.z, bg0.z);
            gene[3] = fmaf(bfhi(xv.y), wg0.w, bg0.w);
            gene[4] = fmaf(bflo(xv.z), wg1.x, bg1.x);
            gene[5] = fmaf(bfhi(xv.z), wg1.y, bg1.y);
            gene[6] = fmaf(bflo(xv.w), wg1.z, bg1.z);
            gene[7] = fmaf(bfhi(xv.w), wg1.w, bg1.w);
            float a0 = 0.f, a1 = 0.f, a2 = 0.f, a3 = 0.f;
#pragma unroll
            for (int g = 0; g < 8; ++g) {
                a0 = fmaf(gene[g], w0r[g].x, a0);
                a1 = fmaf(gene[g], w0r[g].y, a1);
                a2 = fmaf(gene[g], w0r[g].z, a2);
                a3 = fmaf(gene[g], w0r[g].w, a3);
            }
            *(uint2*)(h0base + b * H0S) =
                make_uint2(f2bf2(sigf(a0), sigf(a1)), f2bf2(sigf(a2), sigf(a3)));
        }
    }
    __syncthreads();

    // ---------- phase B: h1 MFMA. wave wv -> modules {2wv, 2wv+1} ----------
    {
#pragma unroll
        for (int jj = 0; jj < 2; ++jj) {
            const int j = wv * 2 + jj;
            const unsigned short* am = &h0s[n * H0S + j * 128 + q * 8];
            floatx4 acc = {0.f, 0.f, 0.f, 0.f};
#pragma unroll
            for (int ks = 0; ks < 4; ++ks) {
                const short8 av = *(const short8*)(am + ks * 32);
                acc = __builtin_amdgcn_mfma_f32_16x16x32_bf16(av, w1r[jj][ks], acc, 0, 0, 0);
            }
#pragma unroll
            for (int r = 0; r < 4; ++r)
                h1u[(q * 4 + r) * H1S + j * 16 + n] = f2bf(sigf(acc[r]));
        }
    }
    __syncthreads();

    // ---------- phase C: h2 MFMA (module s), wave 0 only ----------
    if (wv == 0) {
        const unsigned short* am = &h1u[n * H1S + q * 8];
        floatx4 acc = {0.f, 0.f, 0.f, 0.f};
#pragma unroll
        for (int ks = 0; ks < 4; ++ks) {
            const short8 av = *(const short8*)(am + ks * 32);
            acc = __builtin_amdgcn_mfma_f32_16x16x32_bf16(av, w2r[ks], acc, 0, 0, 0);
        }
#pragma unroll
        for (int r = 0; r < 4; ++r)
            h2ws[(size_t)(b0 + q * 4 + r) * 128 + s * 16 + n] = sigf(acc[r]);
    }

    // ---------- fused root: last slice-block of this tile ----------
    if (wv == 0) __threadfence();           // release h2 writes (wave 0 wrote them)
    if (tid == 0)
        lastflag = (atomicAdd(&cnt[tile], 1) == 7);
    __syncthreads();                        // also orders h1u reads before xs reuse
    if (lastflag) {
        __threadfence();                    // acquire: invalidate stale L1/L2 lines
        float* w3s = (float*)xs;            // 8192 B, xs dead
        float* wfs = (float*)(xs + 4096);   // byte offset 8192
        *(float4*)&w3s[tid * 8]     = *(const float4*)(W3 + tid * 8);
        *(float4*)&w3s[tid * 8 + 4] = *(const float4*)(W3 + tid * 8 + 4);
        if (tid < 16) wfs[tid] = Wf[tid];
        __syncthreads();
        const int h = tid & 15;
        const int b = b0 + (tid >> 4);
        const float4* hp = (const float4*)(h2ws + (size_t)b * 128);
        float acc = 0.f;
#pragma unroll
        for (int k4 = 0; k4 < 32; ++k4) {
            const float4 hv = hp[k4];
            acc = fmaf(hv.x, w3s[(k4 * 4 + 0) * 16 + h], acc);
            acc = fmaf(hv.y, w3s[(k4 * 4 + 1) * 16 + h], acc);
            acc = fmaf(hv.z, w3s[(k4 * 4 + 2) * 16 + h], acc);
            acc = fmaf(hv.w, w3s[(k4 * 4 + 3) * 16 + h], acc);
        }
        float v = sigf(acc) * wfs[h];
        v += __shfl_down(v, 8, 16);
        v += __shfl_down(v, 4, 16);
        v += __shfl_down(v, 2, 16);
        v += __shfl_down(v, 1, 16);
        if (h == 0) out[b] = v;
    }
}

extern "C" void kernel_launch(void* const* d_in, const int* in_sizes, int n_in,
                              void* d_out, int out_size, void* d_ws, size_t ws_size,
                              hipStream_t stream) {
    const float* x  = (const float*)d_in[0];
    const float* Wg = (const float*)d_in[1];
    const float* bg = (const float*)d_in[2];
    const float* W0 = (const float*)d_in[3];
    const float* W1 = (const float*)d_in[4];
    const float* W2 = (const float*)d_in[5];
    const float* W3 = (const float*)d_in[6];
    const float* Wf = (const float*)d_in[7];
    float* out = (float*)d_out;

    unsigned short* W1t = (unsigned short*)d_ws;                          // 256 KB
    unsigned short* W2t = W1t + (size_t)64 * 2048;                        //  32 KB
    int* cnt = (int*)((char*)d_ws + (size_t)288 * 1024);                  //   1 KB
    float* h2 = (float*)((char*)d_ws + (size_t)512 * 1024);               //   2 MB

    k_prep<<<dim3(72), dim3(256), 0, stream>>>(W1, W2, W1t, W2t, cnt);
    k_tree<<<dim3((4096 / TB) * 8), dim3(256), 0, stream>>>(
        x, Wg, bg, W0, W1t, W2t, W3, Wf, h2, cnt, out);
}

// Round 3
// 120.575 us; speedup vs baseline: 2.7620x; 2.7620x over previous
//
#include <hip/hip_runtime.h>
#include <hip/hip_bf16.h>

// RestrictedNN DAG. Round 8: back to the 3-kernel round-5 structure (the
// fence-based root fusion of round 7 caused per-block L2 writebacks: 2.1 GB
// WRITE_SIZE, 10x regression). Changes vs round 5:
//  - k_tree LDS cut 50176 -> 40960 B (4 blocks/CU instead of 3):
//      * h0s pad removed; bank conflicts fixed by XOR swizzle
//        (byte ^= (row&7)<<4 on both write and read sides).
//      * x staged in an 8-row buffer used twice (phase A runs as two
//        8-row passes); all 16 rows still prefetched to registers at entry.
//  - k_root: 256 blocks x 256 threads (16 rows/block, 4 waves).
// Arithmetic identical to round 5 (absmax unchanged).
// B=4096, L0=512 leaves (G=8,H=16), L1=64, L2=8 (FAN=8), root 128->16.

#define TB 16
#define H1S 136      // ushorts per h1 row (128+8): rows 16B-aligned

typedef __attribute__((ext_vector_type(8))) short short8;
typedef __attribute__((ext_vector_type(4))) float floatx4;

__device__ __forceinline__ float sigf(float v) {
    return __builtin_amdgcn_rcpf(1.0f + __expf(-v));
}
__device__ __forceinline__ float bflo(unsigned int p) {
    return __builtin_bit_cast(float, p << 16);
}
__device__ __forceinline__ float bfhi(unsigned int p) {
    return __builtin_bit_cast(float, p & 0xffff0000u);
}
__device__ __forceinline__ unsigned int f2bf_u32(float f) {   // RNE, bf16 in low 16
    unsigned int u = __builtin_bit_cast(unsigned int, f);
    return (u + 0x7fffu + ((u >> 16) & 1u)) >> 16;
}
__device__ __forceinline__ unsigned short f2bf(float f) {
    return (unsigned short)f2bf_u32(f);
}
__device__ __forceinline__ unsigned int f2bf2(float lo, float hi) {
    return f2bf_u32(lo) | (f2bf_u32(hi) << 16);
}

// ---- prep: transpose W1/W2 per module to bf16 [h][k] fragment layout ----
__global__ __launch_bounds__(256) void k_prep(
    const float* __restrict__ W1, const float* __restrict__ W2,
    unsigned short* __restrict__ W1t, unsigned short* __restrict__ W2t)
{
    __shared__ float wl[128 * 17];
    const int mb = blockIdx.x;              // 0..63 -> W1, 64..71 -> W2
    const float* src = (mb < 64) ? (W1 + (size_t)mb * 2048)
                                 : (W2 + (size_t)(mb - 64) * 2048);
    unsigned short* dst = (mb < 64) ? (W1t + (size_t)mb * 2048)
                                    : (W2t + (size_t)(mb - 64) * 2048);
    const int tid = threadIdx.x;
#pragma unroll
    for (int i = 0; i < 8; ++i) {
        const int idx = tid + i * 256;      // [k][h] in, coalesced
        wl[(idx >> 4) * 17 + (idx & 15)] = src[idx];
    }
    __syncthreads();
#pragma unroll
    for (int i = 0; i < 4; ++i) {
        const int u  = tid + i * 256;       // uint index over [h][k] bf16 out
        const int h  = u >> 6;
        const int k  = (u & 63) * 2;
        ((unsigned int*)dst)[u] = f2bf2(wl[k * 17 + h], wl[(k + 1) * 17 + h]);
    }
}

__global__ __launch_bounds__(256) void k_tree(
    const float* __restrict__ x, const float* __restrict__ Wg,
    const float* __restrict__ bg, const float* __restrict__ W0,
    const unsigned short* __restrict__ W1t, const unsigned short* __restrict__ W2t,
    float* __restrict__ h2ws)
{
    __shared__ __align__(16) unsigned short xs[8 * 512];     //  8192 B (2 passes; h1 reuses)
    __shared__ __align__(16) unsigned short h0s[16 * 1024];  // 32768 B, XOR-swizzled rows
    unsigned short* h1u = xs;   // h1 [b][j*16+h] bf16, stride H1S; xs dead after A

    const int tid  = threadIdx.x;
    const int s    = blockIdx.x & 7;
    const int b0   = (blockIdx.x >> 3) * TB;
    const int lane = tid & 63;
    const int wv   = tid >> 6;

    // ---------- issue all 16 rows of x (oldest in pipe), convert as they land
    const float* xbase = x + (size_t)b0 * 4096 + s * 512;
    uint2 xpA[4], xpB[4];
#pragma unroll
    for (int t = 0; t < 4; ++t) {
        const int i = tid + t * 256;           // over 8*128 float4s
        const int r = i >> 7, c4 = i & 127;
        const float4 v = *(const float4*)(xbase + (size_t)r * 4096 + c4 * 4);
        xpA[t] = make_uint2(f2bf2(v.x, v.y), f2bf2(v.z, v.w));
    }
#pragma unroll
    for (int t = 0; t < 4; ++t) {
        const int i = tid + t * 256;
        const int r = (i >> 7) + 8, c4 = i & 127;
        const float4 v = *(const float4*)(xbase + (size_t)r * 4096 + c4 * 4);
        xpB[t] = make_uint2(f2bf2(v.x, v.y), f2bf2(v.z, v.w));
    }

    // ---------- prefetch phase-A weights (lane-contiguous W0) ----------
    const int m_l = tid >> 2;                  // local leaf module 0..63
    const int hq  = tid & 3;                   // h quad
    const int m   = s * 64 + m_l;
    float4 w0r[8];
#pragma unroll
    for (int g = 0; g < 8; ++g)
        w0r[g] = *(const float4*)(W0 + (size_t)m * 128 + g * 16 + hq * 4);
    const float4 wg0 = *(const float4*)(Wg + m * 8);
    const float4 wg1 = *(const float4*)(Wg + m * 8 + 4);
    const float4 bg0 = *(const float4*)(bg + m * 8);
    const float4 bg1 = *(const float4*)(bg + m * 8 + 4);

    // ---------- prefetch phase-B/C MFMA B-fragments ----------
    const int n = lane & 15, q = lane >> 4;
    short8 w1r[2][4];
#pragma unroll
    for (int jj = 0; jj < 2; ++jj) {
        const unsigned short* w1m =
            W1t + ((size_t)(s * 8 + wv * 2 + jj) * 16 + n) * 128 + q * 8;
#pragma unroll
        for (int ks = 0; ks < 4; ++ks)
            w1r[jj][ks] = *(const short8*)(w1m + ks * 32);
    }
    short8 w2r[4];
    if (wv == 0) {
        const unsigned short* w2m = W2t + ((size_t)s * 16 + n) * 128 + q * 8;
#pragma unroll
        for (int ks = 0; ks < 4; ++ks) w2r[ks] = *(const short8*)(w2m + ks * 32);
    }

    // ---------- phase A: two 8-row passes through the small x buffer ----
    char* const h0b = (char*)h0s;
    const int h0off = m_l * 32 + hq * 8;       // logical byte offset in row
#pragma unroll
    for (int t = 0; t < 4; ++t) {              // stage rows 0-7
        const int i = tid + t * 256;
        const int r = i >> 7, c4 = i & 127;
        *(uint2*)&xs[r * 512 + c4 * 4] = xpA[t];
    }
    __syncthreads();
#pragma unroll 1
    for (int st = 0; st < 2; ++st) {
        if (st == 1) {
            __syncthreads();                   // pass-0 reads done
#pragma unroll
            for (int t = 0; t < 4; ++t) {      // stage rows 8-15
                const int i = tid + t * 256;
                const int r = i >> 7, c4 = i & 127;
                *(uint2*)&xs[r * 512 + c4 * 4] = xpB[t];
            }
            __syncthreads();
        }
#pragma unroll 4
        for (int bb = 0; bb < 8; ++bb) {
            const int b = st * 8 + bb;
            const uint4 xv = *(const uint4*)&xs[bb * 512 + m_l * 8];
            float gene[8];
            gene[0] = fmaf(bflo(xv.x), wg0.x, bg0.x);
            gene[1] = fmaf(bfhi(xv.x), wg0.y, bg0.y);
            gene[2] = fmaf(bflo(xv.y), wg0.z, bg0.z);
            gene[3] = fmaf(bfhi(xv.y), wg0.w, bg0.w);
            gene[4] = fmaf(bflo(xv.z), wg1.x, bg1.x);
            gene[5] = fmaf(bfhi(xv.z), wg1.y, bg1.y);
            gene[6] = fmaf(bflo(xv.w), wg1.z, bg1.z);
            gene[7] = fmaf(bfhi(xv.w), wg1.w, bg1.w);
            float a0 = 0.f, a1 = 0.f, a2 = 0.f, a3 = 0.f;
#pragma unroll
            for (int g = 0; g < 8; ++g) {
                a0 = fmaf(gene[g], w0r[g].x, a0);
                a1 = fmaf(gene[g], w0r[g].y, a1);
                a2 = fmaf(gene[g], w0r[g].z, a2);
                a3 = fmaf(gene[g], w0r[g].w, a3);
            }
            // XOR-swizzled store: row b, logical byte off h0off
            *(uint2*)(h0b + b * 2048 + (h0off ^ ((bb & 7) << 4))) =
                make_uint2(f2bf2(sigf(a0), sigf(a1)), f2bf2(sigf(a2), sigf(a3)));
        }
    }
    __syncthreads();

    // ---------- phase B: h1 MFMA. wave wv -> modules {2wv, 2wv+1} ----------
    {
        const int swn = (n & 7) << 4;          // read-side swizzle for row n
#pragma unroll
        for (int jj = 0; jj < 2; ++jj) {
            const int j = wv * 2 + jj;
            floatx4 acc = {0.f, 0.f, 0.f, 0.f};
#pragma unroll
            for (int ks = 0; ks < 4; ++ks) {
                const short8 av = *(const short8*)(h0b + n * 2048 +
                                   ((j * 256 + q * 16 + ks * 64) ^ swn));
                acc = __builtin_amdgcn_mfma_f32_16x16x32_bf16(av, w1r[jj][ks], acc, 0, 0, 0);
            }
#pragma unroll
            for (int r = 0; r < 4; ++r)
                h1u[(q * 4 + r) * H1S + j * 16 + n] = f2bf(sigf(acc[r]));
        }
    }
    __syncthreads();

    // ---------- phase C: h2 MFMA (module s), wave 0 only ----------
    if (wv == 0) {
        const unsigned short* am = &h1u[n * H1S + q * 8];
        floatx4 acc = {0.f, 0.f, 0.f, 0.f};
#pragma unroll
        for (int ks = 0; ks < 4; ++ks) {
            const short8 av = *(const short8*)(am + ks * 32);
            acc = __builtin_amdgcn_mfma_f32_16x16x32_bf16(av, w2r[ks], acc, 0, 0, 0);
        }
#pragma unroll
        for (int r = 0; r < 4; ++r)
            h2ws[(size_t)(b0 + q * 4 + r) * 128 + s * 16 + n] = sigf(acc[r]);
    }
}

// ---------- kernel: root (128->16, sigmoid) + final dot(16) ----------
__global__ __launch_bounds__(256) void k_root(
    const float* __restrict__ h2ws, const float* __restrict__ W3,
    const float* __restrict__ Wf, float* __restrict__ out)
{
    __shared__ float w3s[2048];
    __shared__ float wfs[16];
    const int tid = threadIdx.x;
    *(float4*)&w3s[tid * 8]     = *(const float4*)(W3 + tid * 8);
    *(float4*)&w3s[tid * 8 + 4] = *(const float4*)(W3 + tid * 8 + 4);
    if (tid < 16) wfs[tid] = Wf[tid];
    __syncthreads();

    const int h = tid & 15;
    const int b = blockIdx.x * 16 + (tid >> 4);
    const float4* hp = (const float4*)(h2ws + (size_t)b * 128);
    float acc = 0.f;
#pragma unroll
    for (int k4 = 0; k4 < 32; ++k4) {
        const float4 hv = hp[k4];
        acc = fmaf(hv.x, w3s[(k4 * 4 + 0) * 16 + h], acc);
        acc = fmaf(hv.y, w3s[(k4 * 4 + 1) * 16 + h], acc);
        acc = fmaf(hv.z, w3s[(k4 * 4 + 2) * 16 + h], acc);
        acc = fmaf(hv.w, w3s[(k4 * 4 + 3) * 16 + h], acc);
    }
    float v = sigf(acc) * wfs[h];
    v += __shfl_down(v, 8, 16);
    v += __shfl_down(v, 4, 16);
    v += __shfl_down(v, 2, 16);
    v += __shfl_down(v, 1, 16);
    if (h == 0) out[b] = v;
}

extern "C" void kernel_launch(void* const* d_in, const int* in_sizes, int n_in,
                              void* d_out, int out_size, void* d_ws, size_t ws_size,
                              hipStream_t stream) {
    const float* x  = (const float*)d_in[0];
    const float* Wg = (const float*)d_in[1];
    const float* bg = (const float*)d_in[2];
    const float* W0 = (const float*)d_in[3];
    const float* W1 = (const float*)d_in[4];
    const float* W2 = (const float*)d_in[5];
    const float* W3 = (const float*)d_in[6];
    const float* Wf = (const float*)d_in[7];
    float* out = (float*)d_out;

    float* h2 = (float*)d_ws;                                   // 4096*128 f32 = 2 MB
    unsigned short* W1t = (unsigned short*)((char*)d_ws + (size_t)2 * 1024 * 1024); // 256 KB
    unsigned short* W2t = W1t + (size_t)64 * 2048;                                  // 32 KB

    k_prep<<<dim3(72), dim3(256), 0, stream>>>(W1, W2, W1t, W2t);
    k_tree<<<dim3((4096 / TB) * 8), dim3(256), 0, stream>>>(x, Wg, bg, W0, W1t, W2t, h2);
    k_root<<<dim3(4096 / 16), dim3(256), 0, stream>>>(h2, W3, Wf, out);
}

// Round 4
// 118.821 us; speedup vs baseline: 2.8028x; 1.0148x over previous
//
#include <hip/hip_runtime.h>
#include <hip/hip_bf16.h>

// RestrictedNN DAG. Round 9: phase A on the matrix pipe.
//  - Algebra: gene layer folds into W0:  h0pre = x·(Wg*W0) + (bg·W0).
//    k_prep precomputes W0f = per-module 64-lane A-fragment table of
//    bf16(Wg*W0) (zero-padded K rows) and bias0 (f32).
//  - k_tree phase A: ONE mfma_16x16x32_bf16 per leaf module
//    (A = W0f table, B = staged x bf16 from LDS, C init = bias0 f32).
//    Per module: 1 ds_read_b128 + 1 mfma + 4 sigf + 1 ds_write_b64.
//    Replaces the ~80-VALU-per-row scalar gene/h0 chain.
//  - xs and h0s XOR-swizzled (^((row&7)<<4)); h0s layout identical to
//    round 8, so phases B/C and k_root are unchanged.
// B=4096, L0=512 leaves (G=8,H=16), L1=64, L2=8 (FAN=8), root 128->16.

#define TB 16
#define H1S 136      // ushorts per h1 row (128+8): rows 16B-aligned

typedef __attribute__((ext_vector_type(8))) short short8;
typedef __attribute__((ext_vector_type(4))) float floatx4;

__device__ __forceinline__ float sigf(float v) {
    return __builtin_amdgcn_rcpf(1.0f + __expf(-v));
}
__device__ __forceinline__ unsigned int f2bf_u32(float f) {   // RNE, bf16 in low 16
    unsigned int u = __builtin_bit_cast(unsigned int, f);
    return (u + 0x7fffu + ((u >> 16) & 1u)) >> 16;
}
__device__ __forceinline__ unsigned short f2bf(float f) {
    return (unsigned short)f2bf_u32(f);
}
__device__ __forceinline__ unsigned int f2bf2(float lo, float hi) {
    return f2bf_u32(lo) | (f2bf_u32(hi) << 16);
}

// ---- prep ----
// blocks 0..71 : transpose W1/W2 per module to bf16 [h][k] fragment layout
// blocks 72..135: build W0f (per-module 64-lane A-frag table, bf16 Wg*W0,
//                zero K-pad) and bias0 (f32, = bg . W0)
__global__ __launch_bounds__(256) void k_prep(
    const float* __restrict__ W1, const float* __restrict__ W2,
    const float* __restrict__ Wg, const float* __restrict__ bg,
    const float* __restrict__ W0,
    unsigned short* __restrict__ W1t, unsigned short* __restrict__ W2t,
    unsigned short* __restrict__ W0f, float* __restrict__ bias0g)
{
    __shared__ float wl[128 * 17];
    const int mb  = blockIdx.x;
    const int tid = threadIdx.x;
    if (mb < 72) {
        const float* src = (mb < 64) ? (W1 + (size_t)mb * 2048)
                                     : (W2 + (size_t)(mb - 64) * 2048);
        unsigned short* dst = (mb < 64) ? (W1t + (size_t)mb * 2048)
                                        : (W2t + (size_t)(mb - 64) * 2048);
#pragma unroll
        for (int i = 0; i < 8; ++i) {
            const int idx = tid + i * 256;      // [k][h] in, coalesced
            wl[(idx >> 4) * 17 + (idx & 15)] = src[idx];
        }
        __syncthreads();
#pragma unroll
        for (int i = 0; i < 4; ++i) {
            const int u  = tid + i * 256;       // uint index over [h][k] bf16 out
            const int h  = u >> 6;
            const int k  = (u & 63) * 2;
            ((unsigned int*)dst)[u] = f2bf2(wl[k * 17 + h], wl[(k + 1) * 17 + h]);
        }
    } else {
        const int idx = mb - 72;                // 0..63, 8 modules each
        const int sub = tid >> 6, l = tid & 63;
#pragma unroll
        for (int it = 0; it < 2; ++it) {
            const int m = idx * 8 + it * 4 + sub;
            uint4 v = make_uint4(0u, 0u, 0u, 0u);
            if (l < 16) {
                float p[8];
                float bsum = 0.f;
#pragma unroll
                for (int j = 0; j < 8; ++j) {
                    const float w = W0[(size_t)m * 128 + j * 16 + l];
                    p[j] = Wg[m * 8 + j] * w;
                    bsum = fmaf(bg[m * 8 + j], w, bsum);
                }
                v.x = f2bf2(p[0], p[1]);
                v.y = f2bf2(p[2], p[3]);
                v.z = f2bf2(p[4], p[5]);
                v.w = f2bf2(p[6], p[7]);
                bias0g[m * 16 + l] = bsum;
            }
            *(uint4*)(W0f + (size_t)m * 512 + l * 8) = v;
        }
    }
}

// 2x4-deep software-pipeline regs for phase A (static indices only)
struct FragG { uint4 a0, a1, a2, a3; float4 b0, b1, b2, b3; };

__device__ __forceinline__ void load4(FragG& f, const unsigned short* w0fp,
                                      const float* bp, int g) {
    f.a0 = *(const uint4*)(w0fp + (size_t)(g * 4 + 0) * 512);
    f.a1 = *(const uint4*)(w0fp + (size_t)(g * 4 + 1) * 512);
    f.a2 = *(const uint4*)(w0fp + (size_t)(g * 4 + 2) * 512);
    f.a3 = *(const uint4*)(w0fp + (size_t)(g * 4 + 3) * 512);
    f.b0 = *(const float4*)(bp + (g * 4 + 0) * 16);
    f.b1 = *(const float4*)(bp + (g * 4 + 1) * 16);
    f.b2 = *(const float4*)(bp + (g * 4 + 2) * 16);
    f.b3 = *(const float4*)(bp + (g * 4 + 3) * 16);
}

__device__ __forceinline__ void comp4(const FragG& f, int g, int m0,
                                      const char* xrd, char* h0wr,
                                      int brow, int q) {
#pragma unroll
    for (int i = 0; i < 4; ++i) {
        const uint4  a4 = (i == 0) ? f.a0 : (i == 1) ? f.a1 : (i == 2) ? f.a2 : f.a3;
        const float4 b4 = (i == 0) ? f.b0 : (i == 1) ? f.b1 : (i == 2) ? f.b2 : f.b3;
        const int mloc = m0 + g * 4 + i;
        const short8 bv = *(const short8*)(xrd + ((mloc * 16) ^ ((brow & 7) << 4)));
        floatx4 acc = {b4.x, b4.y, b4.z, b4.w};
        acc = __builtin_amdgcn_mfma_f32_16x16x32_bf16(
                  __builtin_bit_cast(short8, a4), bv, acc, 0, 0, 0);
        *(uint2*)(h0wr + ((mloc * 32 + q * 8) ^ ((brow & 7) << 4))) =
            make_uint2(f2bf2(sigf(acc[0]), sigf(acc[1])),
                       f2bf2(sigf(acc[2]), sigf(acc[3])));
    }
}

__global__ __launch_bounds__(256, 3) void k_tree(
    const float* __restrict__ x,
    const unsigned short* __restrict__ W0f, const float* __restrict__ bias0g,
    const unsigned short* __restrict__ W1t, const unsigned short* __restrict__ W2t,
    float* __restrict__ h2ws)
{
    __shared__ __align__(16) unsigned short xs[16 * 512];     // 16384 B (h1 reuses)
    __shared__ __align__(16) unsigned short h0s[16 * 1024];   // 32768 B, swizzled
    unsigned short* h1u = xs;   // h1 [b][j*16+h] bf16, stride H1S; xs dead after A

    const int tid  = threadIdx.x;
    const int s    = blockIdx.x & 7;
    const int b0   = (blockIdx.x >> 3) * TB;
    const int lane = tid & 63;
    const int wv   = tid >> 6;
    const int n    = lane & 15, q = lane >> 4;

    // ---------- issue x stage loads (oldest in pipe), convert as they land ----
    const float* xbase = x + (size_t)b0 * 4096 + s * 512;
    uint2 xp[8];
#pragma unroll
    for (int t = 0; t < 8; ++t) {
        const int i = tid + t * 256;           // over TB*128 float4s
        const int r = i >> 7, c4 = i & 127;
        const float4 v = *(const float4*)(xbase + (size_t)r * 4096 + c4 * 4);
        xp[t] = make_uint2(f2bf2(v.x, v.y), f2bf2(v.z, v.w));
    }

    // ---------- prefetch phase-B/C MFMA B-fragments ----------
    short8 w1r[2][4];
#pragma unroll
    for (int jj = 0; jj < 2; ++jj) {
        const unsigned short* w1m =
            W1t + ((size_t)(s * 8 + wv * 2 + jj) * 16 + n) * 128 + q * 8;
#pragma unroll
        for (int ks = 0; ks < 4; ++ks)
            w1r[jj][ks] = *(const short8*)(w1m + ks * 32);
    }
    short8 w2r[4];
    if (wv == 0) {
        const unsigned short* w2m = W2t + ((size_t)s * 16 + n) * 128 + q * 8;
#pragma unroll
        for (int ks = 0; ks < 4; ++ks) w2r[ks] = *(const short8*)(w2m + ks * 32);
    }

    // ---------- write x tile to LDS (swizzled rows) ----------
#pragma unroll
    for (int t = 0; t < 8; ++t) {
        const int i = tid + t * 256;
        const int r = i >> 7, c4 = i & 127;
        *(uint2*)((char*)xs + r * 1024 + ((c4 * 8) ^ ((r & 7) << 4))) = xp[t];
    }
    __syncthreads();

    // ---------- phase A: one MFMA per leaf module ----------
    // wave wv owns local modules [wv*16, wv*16+16). Lane roles:
    //   A-frag: per-lane 16B row of W0f table (lanes>=16 hold zero K-pad)
    //   B-frag: x row (batch = lane&15), genes of module mloc
    //   D: col = batch = lane&15, rows h = q*4+r  -> one b64 write/module
    {
        const int m0 = wv * 16;
        const unsigned short* w0fp = W0f + ((size_t)(s * 64 + m0) * 64 + lane) * 8;
        const float* bp = bias0g + (size_t)(s * 64 + m0) * 16 + q * 4;
        const int brow = lane & 15;
        const char* xrd = (const char*)xs + brow * 1024;
        char* h0wr = (char*)h0s + brow * 2048;
        FragG fA, fB;
        load4(fA, w0fp, bp, 0);
        load4(fB, w0fp, bp, 1);
        comp4(fA, 0, m0, xrd, h0wr, brow, q);
        load4(fA, w0fp, bp, 2);
        comp4(fB, 1, m0, xrd, h0wr, brow, q);
        load4(fB, w0fp, bp, 3);
        comp4(fA, 2, m0, xrd, h0wr, brow, q);
        comp4(fB, 3, m0, xrd, h0wr, brow, q);
    }
    __syncthreads();

    // ---------- phase B: h1 MFMA. wave wv -> modules {2wv, 2wv+1} ----------
    {
        char* const h0b = (char*)h0s;
        const int swn = (n & 7) << 4;          // read-side swizzle for row n
#pragma unroll
        for (int jj = 0; jj < 2; ++jj) {
            const int j = wv * 2 + jj;
            floatx4 acc = {0.f, 0.f, 0.f, 0.f};
#pragma unroll
            for (int ks = 0; ks < 4; ++ks) {
                const short8 av = *(const short8*)(h0b + n * 2048 +
                                   ((j * 256 + q * 16 + ks * 64) ^ swn));
                acc = __builtin_amdgcn_mfma_f32_16x16x32_bf16(av, w1r[jj][ks], acc, 0, 0, 0);
            }
#pragma unroll
            for (int r = 0; r < 4; ++r)
                h1u[(q * 4 + r) * H1S + j * 16 + n] = f2bf(sigf(acc[r]));
        }
    }
    __syncthreads();

    // ---------- phase C: h2 MFMA (module s), wave 0 only ----------
    if (wv == 0) {
        const unsigned short* am = &h1u[n * H1S + q * 8];
        floatx4 acc = {0.f, 0.f, 0.f, 0.f};
#pragma unroll
        for (int ks = 0; ks < 4; ++ks) {
            const short8 av = *(const short8*)(am + ks * 32);
            acc = __builtin_amdgcn_mfma_f32_16x16x32_bf16(av, w2r[ks], acc, 0, 0, 0);
        }
#pragma unroll
        for (int r = 0; r < 4; ++r)
            h2ws[(size_t)(b0 + q * 4 + r) * 128 + s * 16 + n] = sigf(acc[r]);
    }
}

// ---------- kernel: root (128->16, sigmoid) + final dot(16) ----------
__global__ __launch_bounds__(256) void k_root(
    const float* __restrict__ h2ws, const float* __restrict__ W3,
    const float* __restrict__ Wf, float* __restrict__ out)
{
    __shared__ float w3s[2048];
    __shared__ float wfs[16];
    const int tid = threadIdx.x;
    *(float4*)&w3s[tid * 8]     = *(const float4*)(W3 + tid * 8);
    *(float4*)&w3s[tid * 8 + 4] = *(const float4*)(W3 + tid * 8 + 4);
    if (tid < 16) wfs[tid] = Wf[tid];
    __syncthreads();

    const int h = tid & 15;
    const int b = blockIdx.x * 16 + (tid >> 4);
    const float4* hp = (const float4*)(h2ws + (size_t)b * 128);
    float acc = 0.f;
#pragma unroll
    for (int k4 = 0; k4 < 32; ++k4) {
        const float4 hv = hp[k4];
        acc = fmaf(hv.x, w3s[(k4 * 4 + 0) * 16 + h], acc);
        acc = fmaf(hv.y, w3s[(k4 * 4 + 1) * 16 + h], acc);
        acc = fmaf(hv.z, w3s[(k4 * 4 + 2) * 16 + h], acc);
        acc = fmaf(hv.w, w3s[(k4 * 4 + 3) * 16 + h], acc);
    }
    float v = sigf(acc) * wfs[h];
    v += __shfl_down(v, 8, 16);
    v += __shfl_down(v, 4, 16);
    v += __shfl_down(v, 2, 16);
    v += __shfl_down(v, 1, 16);
    if (h == 0) out[b] = v;
}

extern "C" void kernel_launch(void* const* d_in, const int* in_sizes, int n_in,
                              void* d_out, int out_size, void* d_ws, size_t ws_size,
                              hipStream_t stream) {
    const float* x  = (const float*)d_in[0];
    const float* Wg = (const float*)d_in[1];
    const float* bg = (const float*)d_in[2];
    const float* W0 = (const float*)d_in[3];
    const float* W1 = (const float*)d_in[4];
    const float* W2 = (const float*)d_in[5];
    const float* W3 = (const float*)d_in[6];
    const float* Wf = (const float*)d_in[7];
    float* out = (float*)d_out;

    float* h2 = (float*)d_ws;                                          // 2 MB
    unsigned short* W1t = (unsigned short*)((char*)d_ws + (size_t)2 * 1024 * 1024); // 256 KB
    unsigned short* W2t = W1t + (size_t)64 * 2048;                                  //  32 KB
    unsigned short* W0f = (unsigned short*)((char*)d_ws + (size_t)2 * 1024 * 1024
                                                        + (size_t)512 * 1024);      // 512 KB
    float* bias0g = (float*)((char*)d_ws + (size_t)3 * 1024 * 1024);                //  32 KB

    k_prep<<<dim3(136), dim3(256), 0, stream>>>(W1, W2, Wg, bg, W0,
                                                W1t, W2t, W0f, bias0g);
    k_tree<<<dim3((4096 / TB) * 8), dim3(256), 0, stream>>>(
        x, W0f, bias0g, W1t, W2t, h2);
    k_root<<<dim3(4096 / 16), dim3(256), 0, stream>>>(h2, W3, Wf, out);
}

// Round 6
// 117.594 us; speedup vs baseline: 2.8321x; 1.0104x over previous
//
#include <hip/hip_runtime.h>
#include <hip/hip_bf16.h>

// RestrictedNN DAG. Round 10b: round-10 with the compile fix —
// __builtin_bit_cast on __hip_bfloat16x types is rejected (not trivially
// copyable); use __builtin_memcpy type-pun instead. Intent unchanged:
// HIP bf16 cast intrinsics so the compiler emits v_cvt_pk_bf16_f32
// (1 instr/pair vs ~11 for the hand-rolled integer RNE). Bit-identical
// RNE for finite values -> absmax unchanged. Everything else identical
// to round 9 (phase A on matrix pipe via folded Wg*W0 fragment table;
// XOR-swizzled xs/h0s; 3-kernel structure).
// B=4096, L0=512 leaves (G=8,H=16), L1=64, L2=8 (FAN=8), root 128->16.

#define TB 16
#define H1S 136      // ushorts per h1 row (128+8): rows 16B-aligned

typedef __attribute__((ext_vector_type(8))) short short8;
typedef __attribute__((ext_vector_type(4))) float floatx4;

__device__ __forceinline__ float sigf(float v) {
    return __builtin_amdgcn_rcpf(1.0f + __expf(-v));
}
// packed f32x2 -> bf16x2 (RNE). Compiler emits v_cvt_pk_bf16_f32.
__device__ __forceinline__ unsigned int f2bf2(float lo, float hi) {
    __hip_bfloat162 p = __float22bfloat162_rn(make_float2(lo, hi));
    unsigned int u;
    __builtin_memcpy(&u, &p, 4);
    return u;
}
__device__ __forceinline__ unsigned short f2bf(float f) {
    __hip_bfloat16 b = __float2bfloat16(f);
    unsigned short u;
    __builtin_memcpy(&u, &b, 2);
    return u;
}

// ---- prep ----
// blocks 0..71 : transpose W1/W2 per module to bf16 [h][k] fragment layout
// blocks 72..135: build W0f (per-module 64-lane A-frag table, bf16 Wg*W0,
//                zero K-pad) and bias0 (f32, = bg . W0)
__global__ __launch_bounds__(256) void k_prep(
    const float* __restrict__ W1, const float* __restrict__ W2,
    const float* __restrict__ Wg, const float* __restrict__ bg,
    const float* __restrict__ W0,
    unsigned short* __restrict__ W1t, unsigned short* __restrict__ W2t,
    unsigned short* __restrict__ W0f, float* __restrict__ bias0g)
{
    __shared__ float wl[128 * 17];
    const int mb  = blockIdx.x;
    const int tid = threadIdx.x;
    if (mb < 72) {
        const float* src = (mb < 64) ? (W1 + (size_t)mb * 2048)
                                     : (W2 + (size_t)(mb - 64) * 2048);
        unsigned short* dst = (mb < 64) ? (W1t + (size_t)mb * 2048)
                                        : (W2t + (size_t)(mb - 64) * 2048);
#pragma unroll
        for (int i = 0; i < 8; ++i) {
            const int idx = tid + i * 256;      // [k][h] in, coalesced
            wl[(idx >> 4) * 17 + (idx & 15)] = src[idx];
        }
        __syncthreads();
#pragma unroll
        for (int i = 0; i < 4; ++i) {
            const int u  = tid + i * 256;       // uint index over [h][k] bf16 out
            const int h  = u >> 6;
            const int k  = (u & 63) * 2;
            ((unsigned int*)dst)[u] = f2bf2(wl[k * 17 + h], wl[(k + 1) * 17 + h]);
        }
    } else {
        const int idx = mb - 72;                // 0..63, 8 modules each
        const int sub = tid >> 6, l = tid & 63;
#pragma unroll
        for (int it = 0; it < 2; ++it) {
            const int m = idx * 8 + it * 4 + sub;
            uint4 v = make_uint4(0u, 0u, 0u, 0u);
            if (l < 16) {
                float p[8];
                float bsum = 0.f;
#pragma unroll
                for (int j = 0; j < 8; ++j) {
                    const float w = W0[(size_t)m * 128 + j * 16 + l];
                    p[j] = Wg[m * 8 + j] * w;
                    bsum = fmaf(bg[m * 8 + j], w, bsum);
                }
                v.x = f2bf2(p[0], p[1]);
                v.y = f2bf2(p[2], p[3]);
                v.z = f2bf2(p[4], p[5]);
                v.w = f2bf2(p[6], p[7]);
                bias0g[m * 16 + l] = bsum;
            }
            *(uint4*)(W0f + (size_t)m * 512 + l * 8) = v;
        }
    }
}

// 2x4-deep software-pipeline regs for phase A (static indices only)
struct FragG { uint4 a0, a1, a2, a3; float4 b0, b1, b2, b3; };

__device__ __forceinline__ void load4(FragG& f, const unsigned short* w0fp,
                                      const float* bp, int g) {
    f.a0 = *(const uint4*)(w0fp + (size_t)(g * 4 + 0) * 512);
    f.a1 = *(const uint4*)(w0fp + (size_t)(g * 4 + 1) * 512);
    f.a2 = *(const uint4*)(w0fp + (size_t)(g * 4 + 2) * 512);
    f.a3 = *(const uint4*)(w0fp + (size_t)(g * 4 + 3) * 512);
    f.b0 = *(const float4*)(bp + (g * 4 + 0) * 16);
    f.b1 = *(const float4*)(bp + (g * 4 + 1) * 16);
    f.b2 = *(const float4*)(bp + (g * 4 + 2) * 16);
    f.b3 = *(const float4*)(bp + (g * 4 + 3) * 16);
}

__device__ __forceinline__ void comp4(const FragG& f, int g, int m0,
                                      const char* xrd, char* h0wr,
                                      int brow, int q) {
#pragma unroll
    for (int i = 0; i < 4; ++i) {
        const uint4  a4 = (i == 0) ? f.a0 : (i == 1) ? f.a1 : (i == 2) ? f.a2 : f.a3;
        const float4 b4 = (i == 0) ? f.b0 : (i == 1) ? f.b1 : (i == 2) ? f.b2 : f.b3;
        const int mloc = m0 + g * 4 + i;
        const short8 bv = *(const short8*)(xrd + ((mloc * 16) ^ ((brow & 7) << 4)));
        floatx4 acc = {b4.x, b4.y, b4.z, b4.w};
        acc = __builtin_amdgcn_mfma_f32_16x16x32_bf16(
                  __builtin_bit_cast(short8, a4), bv, acc, 0, 0, 0);
        *(uint2*)(h0wr + ((mloc * 32 + q * 8) ^ ((brow & 7) << 4))) =
            make_uint2(f2bf2(sigf(acc[0]), sigf(acc[1])),
                       f2bf2(sigf(acc[2]), sigf(acc[3])));
    }
}

__global__ __launch_bounds__(256, 3) void k_tree(
    const float* __restrict__ x,
    const unsigned short* __restrict__ W0f, const float* __restrict__ bias0g,
    const unsigned short* __restrict__ W1t, const unsigned short* __restrict__ W2t,
    float* __restrict__ h2ws)
{
    __shared__ __align__(16) unsigned short xs[16 * 512];     // 16384 B (h1 reuses)
    __shared__ __align__(16) unsigned short h0s[16 * 1024];   // 32768 B, swizzled
    unsigned short* h1u = xs;   // h1 [b][j*16+h] bf16, stride H1S; xs dead after A

    const int tid  = threadIdx.x;
    const int s    = blockIdx.x & 7;
    const int b0   = (blockIdx.x >> 3) * TB;
    const int lane = tid & 63;
    const int wv   = tid >> 6;
    const int n    = lane & 15, q = lane >> 4;

    // ---------- issue x stage loads (oldest in pipe), convert as they land ----
    const float* xbase = x + (size_t)b0 * 4096 + s * 512;
    uint2 xp[8];
#pragma unroll
    for (int t = 0; t < 8; ++t) {
        const int i = tid + t * 256;           // over TB*128 float4s
        const int r = i >> 7, c4 = i & 127;
        const float4 v = *(const float4*)(xbase + (size_t)r * 4096 + c4 * 4);
        xp[t] = make_uint2(f2bf2(v.x, v.y), f2bf2(v.z, v.w));
    }

    // ---------- prefetch phase-B/C MFMA B-fragments ----------
    short8 w1r[2][4];
#pragma unroll
    for (int jj = 0; jj < 2; ++jj) {
        const unsigned short* w1m =
            W1t + ((size_t)(s * 8 + wv * 2 + jj) * 16 + n) * 128 + q * 8;
#pragma unroll
        for (int ks = 0; ks < 4; ++ks)
            w1r[jj][ks] = *(const short8*)(w1m + ks * 32);
    }
    short8 w2r[4];
    if (wv == 0) {
        const unsigned short* w2m = W2t + ((size_t)s * 16 + n) * 128 + q * 8;
#pragma unroll
        for (int ks = 0; ks < 4; ++ks) w2r[ks] = *(const short8*)(w2m + ks * 32);
    }

    // ---------- write x tile to LDS (swizzled rows) ----------
#pragma unroll
    for (int t = 0; t < 8; ++t) {
        const int i = tid + t * 256;
        const int r = i >> 7, c4 = i & 127;
        *(uint2*)((char*)xs + r * 1024 + ((c4 * 8) ^ ((r & 7) << 4))) = xp[t];
    }
    __syncthreads();

    // ---------- phase A: one MFMA per leaf module ----------
    // wave wv owns local modules [wv*16, wv*16+16). Lane roles:
    //   A-frag: per-lane 16B row of W0f table (lanes>=16 hold zero K-pad)
    //   B-frag: x row (batch = lane&15), genes of module mloc
    //   D: col = batch = lane&15, rows h = q*4+r  -> one b64 write/module
    {
        const int m0 = wv * 16;
        const unsigned short* w0fp = W0f + ((size_t)(s * 64 + m0) * 64 + lane) * 8;
        const float* bp = bias0g + (size_t)(s * 64 + m0) * 16 + q * 4;
        const int brow = lane & 15;
        const char* xrd = (const char*)xs + brow * 1024;
        char* h0wr = (char*)h0s + brow * 2048;
        FragG fA, fB;
        load4(fA, w0fp, bp, 0);
        load4(fB, w0fp, bp, 1);
        comp4(fA, 0, m0, xrd, h0wr, brow, q);
        load4(fA, w0fp, bp, 2);
        comp4(fB, 1, m0, xrd, h0wr, brow, q);
        load4(fB, w0fp, bp, 3);
        comp4(fA, 2, m0, xrd, h0wr, brow, q);
        comp4(fB, 3, m0, xrd, h0wr, brow, q);
    }
    __syncthreads();

    // ---------- phase B: h1 MFMA. wave wv -> modules {2wv, 2wv+1} ----------
    {
        char* const h0b = (char*)h0s;
        const int swn = (n & 7) << 4;          // read-side swizzle for row n
#pragma unroll
        for (int jj = 0; jj < 2; ++jj) {
            const int j = wv * 2 + jj;
            floatx4 acc = {0.f, 0.f, 0.f, 0.f};
#pragma unroll
            for (int ks = 0; ks < 4; ++ks) {
                const short8 av = *(const short8*)(h0b + n * 2048 +
                                   ((j * 256 + q * 16 + ks * 64) ^ swn));
                acc = __builtin_amdgcn_mfma_f32_16x16x32_bf16(av, w1r[jj][ks], acc, 0, 0, 0);
            }
#pragma unroll
            for (int r = 0; r < 4; ++r)
                h1u[(q * 4 + r) * H1S + j * 16 + n] = f2bf(sigf(acc[r]));
        }
    }
    __syncthreads();

    // ---------- phase C: h2 MFMA (module s), wave 0 only ----------
    if (wv == 0) {
        const unsigned short* am = &h1u[n * H1S + q * 8];
        floatx4 acc = {0.f, 0.f, 0.f, 0.f};
#pragma unroll
        for (int ks = 0; ks < 4; ++ks) {
            const short8 av = *(const short8*)(am + ks * 32);
            acc = __builtin_amdgcn_mfma_f32_16x16x32_bf16(av, w2r[ks], acc, 0, 0, 0);
        }
#pragma unroll
        for (int r = 0; r < 4; ++r)
            h2ws[(size_t)(b0 + q * 4 + r) * 128 + s * 16 + n] = sigf(acc[r]);
    }
}

// ---------- kernel: root (128->16, sigmoid) + final dot(16) ----------
__global__ __launch_bounds__(256) void k_root(
    const float* __restrict__ h2ws, const float* __restrict__ W3,
    const float* __restrict__ Wf, float* __restrict__ out)
{
    __shared__ float w3s[2048];
    __shared__ float wfs[16];
    const int tid = threadIdx.x;
    *(float4*)&w3s[tid * 8]     = *(const float4*)(W3 + tid * 8);
    *(float4*)&w3s[tid * 8 + 4] = *(const float4*)(W3 + tid * 8 + 4);
    if (tid < 16) wfs[tid] = Wf[tid];
    __syncthreads();

    const int h = tid & 15;
    const int b = blockIdx.x * 16 + (tid >> 4);
    const float4* hp = (const float4*)(h2ws + (size_t)b * 128);
    float acc = 0.f;
#pragma unroll
    for (int k4 = 0; k4 < 32; ++k4) {
        const float4 hv = hp[k4];
        acc = fmaf(hv.x, w3s[(k4 * 4 + 0) * 16 + h], acc);
        acc = fmaf(hv.y, w3s[(k4 * 4 + 1) * 16 + h], acc);
        acc = fmaf(hv.z, w3s[(k4 * 4 + 2) * 16 + h], acc);
        acc = fmaf(hv.w, w3s[(k4 * 4 + 3) * 16 + h], acc);
    }
    float v = sigf(acc) * wfs[h];
    v += __shfl_down(v, 8, 16);
    v += __shfl_down(v, 4, 16);
    v += __shfl_down(v, 2, 16);
    v += __shfl_down(v, 1, 16);
    if (h == 0) out[b] = v;
}

extern "C" void kernel_launch(void* const* d_in, const int* in_sizes, int n_in,
                              void* d_out, int out_size, void* d_ws, size_t ws_size,
                              hipStream_t stream) {
    const float* x  = (const float*)d_in[0];
    const float* Wg = (const float*)d_in[1];
    const float* bg = (const float*)d_in[2];
    const float* W0 = (const float*)d_in[3];
    const float* W1 = (const float*)d_in[4];
    const float* W2 = (const float*)d_in[5];
    const float* W3 = (const float*)d_in[6];
    const float* Wf = (const float*)d_in[7];
    float* out = (float*)d_out;

    float* h2 = (float*)d_ws;                                          // 2 MB
    unsigned short* W1t = (unsigned short*)((char*)d_ws + (size_t)2 * 1024 * 1024); // 256 KB
    unsigned short* W2t = W1t + (size_t)64 * 2048;                                  //  32 KB
    unsigned short* W0f = (unsigned short*)((char*)d_ws + (size_t)2 * 1024 * 1024
                                                        + (size_t)512 * 1024);      // 512 KB
    float* bias0g = (float*)((char*)d_ws + (size_t)3 * 1024 * 1024);                //  32 KB

    k_prep<<<dim3(136), dim3(256), 0, stream>>>(W1, W2, Wg, bg, W0,
                                                W1t, W2t, W0f, bias0g);
    k_tree<<<dim3((4096 / TB) * 8), dim3(256), 0, stream>>>(
        x, W0f, bias0g, W1t, W2t, h2);
    k_root<<<dim3(4096 / 16), dim3(256), 0, stream>>>(h2, W3, Wf, out);
}